// Round 3
// baseline (72.610 us; speedup 1.0000x reference)
//
#include <hip/hip_runtime.h>

#define BS   128
#define SEQ  64
#define DD   64
#define HH   128
#define G4   512   // 4*H
#define OUTN 4

typedef float    f32x4 __attribute__((ext_vector_type(4)));
typedef float    f32x2 __attribute__((ext_vector_type(2)));

__device__ __forceinline__ float sigm(float v) {
    return __builtin_amdgcn_rcpf(1.0f + __expf(-v));
}

// quad_perm DPP: swap lane^1 (0xB1) and lane^2 (0x4E) within each quad. VALU only.
// swap1 hardware-proven in round 0; 0x4E = [2,3,0,1] = lane^2 by the same encoding.
__device__ __forceinline__ float swap1(float v) {
    return __builtin_bit_cast(float,
        __builtin_amdgcn_mov_dpp(__builtin_bit_cast(int, v), 0xB1, 0xF, 0xF, false));
}
__device__ __forceinline__ float swap2(float v) {
    return __builtin_bit_cast(float,
        __builtin_amdgcn_mov_dpp(__builtin_bit_cast(int, v), 0x4E, 0xF, 0xF, false));
}

// ============================================================================
// Kernel 1: attention context (state term constant over s -> cancels in the
// seq-softmax -> ctx is step-invariant). One block per batch. r11/r16-proven.
// ============================================================================
__global__ void __launch_bounds__(256) ctx_kernel(
    const float* __restrict__ x,    // [BS, SEQ, DD]
    const float* __restrict__ Wa,   // [DD+4H, DD] (rows >= DD cancel)
    float* __restrict__ ctx_ws)     // [BS, DD]
{
    const int batch = blockIdx.x;
    const int t     = threadIdx.x;
    const int lane  = t & 63;

    __shared__ float xs[SEQ * DD];
    __shared__ float was[DD * DD];
    __shared__ float xa[SEQ * DD];
    __shared__ float pmax[4 * 64], psum[4 * 64], pctx[4 * 64];
    __shared__ float fmx[DD];

    const float* xb = x + (size_t)batch * SEQ * DD;
    for (int i = t; i < SEQ * DD; i += 256) {
        xs[i]  = xb[i];
        was[i] = Wa[i];
    }
    __syncthreads();

    {   // XA = x_b @ Wa_x, register-tiled (d = lane, 16 s-rows)
        const int d  = lane;
        const int sb = (t >> 6) * 16;
        float acc[16];
        #pragma unroll
        for (int i = 0; i < 16; ++i) acc[i] = 0.0f;
        for (int kk = 0; kk < 16; ++kk) {
            float wk0 = was[(4 * kk + 0) * DD + d];
            float wk1 = was[(4 * kk + 1) * DD + d];
            float wk2 = was[(4 * kk + 2) * DD + d];
            float wk3 = was[(4 * kk + 3) * DD + d];
            #pragma unroll
            for (int i = 0; i < 16; ++i) {
                float4 xv = *(const float4*)&xs[(sb + i) * DD + 4 * kk];
                acc[i] = fmaf(xv.x, wk0, fmaf(xv.y, wk1,
                         fmaf(xv.z, wk2, fmaf(xv.w, wk3, acc[i]))));
            }
        }
        #pragma unroll
        for (int i = 0; i < 16; ++i) xa[(sb + i) * DD + d] = acc[i];
    }
    __syncthreads();

    {   // softmax partials over s
        const int d = lane, g4 = t >> 6;
        float m = -1e30f;
        #pragma unroll
        for (int j = 0; j < 16; ++j) m = fmaxf(m, xa[(g4 * 16 + j) * DD + d]);
        pmax[g4 * 64 + d] = m;
    }
    __syncthreads();
    if (t < DD) {
        float m = -1e30f;
        #pragma unroll
        for (int g = 0; g < 4; ++g) m = fmaxf(m, pmax[g * 64 + t]);
        fmx[t] = m;
    }
    __syncthreads();
    {
        const int d = lane, g4 = t >> 6;
        const float m = fmx[d];
        float sm = 0.0f, cc = 0.0f;
        #pragma unroll
        for (int j = 0; j < 16; ++j) {
            const int s = g4 * 16 + j;
            float e = __expf(xa[s * DD + d] - m);
            sm += e;
            cc += e * xs[s * DD + d];
        }
        psum[g4 * 64 + d] = sm;
        pctx[g4 * 64 + d] = cc;
    }
    __syncthreads();
    if (t < DD) {
        float sm = 0.0f, cc = 0.0f;
        #pragma unroll
        for (int g = 0; g < 4; ++g) { sm += psum[g * 64 + t]; cc += pctx[g * 64 + t]; }
        ctx_ws[batch * DD + t] = cc / sm;
    }
}

// ============================================================================
// Kernel 2: recurrence on the VALU, FULL F32 (round-2's fdot2/f16 packing was
// the correctness suspect; both removed). Partition unchanged:
//   512 thr, lane = (h-col j = w*16 + l>>2) x (k-quarter kq = l&3).
// Each lane: k-quarter partial of all 4 gates of col j via float2 ops
// (v_pk_fma_f32: 64 pk_fma/lane/step), then 2-round quad-DPP reduce
// (lane^1, lane^2) -> all 4 gates lane-local. Nonlin redundant per quad
// (bit-identical). ONE barrier/step, dbuf 2x512B f32 h in LDS.
// No f16 anywhere -> absmax ~1e-5 (reassoc + __expf/rcp only).
// ============================================================================
__global__ void __launch_bounds__(512, 2) rec_kernel(
    const float* __restrict__ ctx_ws,   // [BS, DD]
    const float* __restrict__ Wi,  const float* __restrict__ Wh,
    const float* __restrict__ b,
    const float* __restrict__ Wvi, const float* __restrict__ Wvh,
    const float* __restrict__ bv,
    float* __restrict__ hfinal)         // [BS, 2H] f32
{
    const int batch = blockIdx.x >> 1;
    const int cell  = blockIdx.x & 1;
    const int t     = threadIdx.x;
    const int w     = t >> 6;           // wave 0..7
    const int l     = t & 63;
    const int jl    = l >> 2;
    const int kq    = l & 3;            // k-quarter (32 h elems)
    const int j     = w * 16 + jl;      // my h column 0..127

    const float* __restrict__ Wx   = cell ? Wvi : Wi;
    const float* __restrict__ Whh  = cell ? Wvh : Wh;
    const float* __restrict__ bias = cell ? bv  : b;

    __shared__ __align__(16) float hs[2][HH];   // dbuf h (f32), 1 KB

    if (t < 256) ((unsigned*)hs)[t] = 0u;       // zero both buffers

    // ---- zx[tau] = bias + ctx @ Wx for col tau*HH+j (f32, redundant/quad) ----
    float zx0 = bias[0 * HH + j], zx1 = bias[1 * HH + j];
    float zx2 = bias[2 * HH + j], zx3 = bias[3 * HH + j];
    {
        const float* ctxp = ctx_ws + batch * DD;
        for (int k = 0; k < DD; ++k) {
            const float cv = ctxp[k];
            const float* wr = Wx + k * G4 + j;
            zx0 = fmaf(cv, wr[0 * HH], zx0);
            zx1 = fmaf(cv, wr[1 * HH], zx1);
            zx2 = fmaf(cv, wr[2 * HH], zx2);
            zx3 = fmaf(cv, wr[3 * HH], zx3);
        }
    }

    // ---- Whh k-slice, f32 float2 pairs: rows kq*32+2kk, kq*32+2kk+1,
    //      gate cols tau*HH+j. 128 VGPRs, fully static indexing. ----
    f32x2 wv[4][16];
    #pragma unroll
    for (int tau = 0; tau < 4; ++tau) {
        const float* wc = Whh + (size_t)(kq * 32) * G4 + tau * HH + j;
        #pragma unroll
        for (int kk = 0; kk < 16; ++kk) {
            f32x2 p;
            p.x = wc[(2 * kk)     * G4];
            p.y = wc[(2 * kk + 1) * G4];
            wv[tau][kk] = p;
        }
    }

    float c_state = 0.0f, h_last = 0.0f;
    __syncthreads();

    int pb = 0;
    for (int step = 0; step < SEQ; ++step) {
        // my 128B k-slice of h: 8 x ds_read_b128, 4 distinct addrs/wave
        const f32x4* hp = (const f32x4*)((const char*)hs[pb] + kq * 128);
        f32x2 a0 = {0.0f, 0.0f}, a1 = a0, a2 = a0, a3 = a0;
        #pragma unroll
        for (int q = 0; q < 8; ++q) {
            const f32x4 hv = hp[q];
            const f32x2 hA = {hv[0], hv[1]};
            const f32x2 hB = {hv[2], hv[3]};
            a0 = hA * wv[0][2 * q] + a0;  a0 = hB * wv[0][2 * q + 1] + a0;
            a1 = hA * wv[1][2 * q] + a1;  a1 = hB * wv[1][2 * q + 1] + a1;
            a2 = hA * wv[2][2 * q] + a2;  a2 = hB * wv[2][2 * q + 1] + a2;
            a3 = hA * wv[3][2 * q] + a3;  a3 = hB * wv[3][2 * q + 1] + a3;
        }
        float p0 = a0[0] + a0[1], p1 = a1[0] + a1[1];
        float p2 = a2[0] + a2[1], p3 = a3[0] + a3[1];

        // quad reduce: sum the 4 k-quarters -> full h@Whh in every quad lane
        p0 += swap1(p0); p0 += swap2(p0);
        p1 += swap1(p1); p1 += swap2(p1);
        p2 += swap1(p2); p2 += swap2(p2);
        p3 += swap1(p3); p3 += swap2(p3);

        const float gi = zx0 + p0, gf = zx1 + p1, gg = zx2 + p2, go = zx3 + p3;
        const float tg = 2.0f * sigm(2.0f * gg) - 1.0f;             // tanh(g)
        c_state  = sigm(gf) * c_state + sigm(gi) * tg;
        const float hn = sigm(go) * (2.0f * sigm(2.0f * c_state) - 1.0f);
        h_last = hn;

        if (kq == 0)
            hs[pb ^ 1][j] = hn;
        __syncthreads();
        pb ^= 1;
    }

    if (kq == 0)
        hfinal[batch * (2 * HH) + cell * HH + j] = h_last;
}

// ============================================================================
// Kernel 3: out[b,o] = bfc[o] + sum_k hfinal[b,k] * Wfc[k,o]
// ============================================================================
__global__ void __launch_bounds__(512) chaotic_out(
    const float* __restrict__ hfinal,  // [BS, 2H] f32
    const float* __restrict__ Wfc,     // [2H, OUTN]
    const float* __restrict__ bfc,     // [OUTN]
    float* __restrict__ out)           // [BS, OUTN]
{
    int idx = threadIdx.x;
    if (idx >= BS * OUTN) return;
    const int bt = idx >> 2;
    const int o  = idx & 3;
    float acc = bfc[o];
    const float* hrow = hfinal + bt * (2 * HH);
    #pragma unroll 8
    for (int k = 0; k < 2 * HH; k++)
        acc = fmaf(hrow[k], Wfc[k * OUTN + o], acc);
    out[idx] = acc;
}

extern "C" void kernel_launch(void* const* d_in, const int* in_sizes, int n_in,
                              void* d_out, int out_size, void* d_ws, size_t ws_size,
                              hipStream_t stream) {
    const float* x   = (const float*)d_in[0];
    const float* Wa  = (const float*)d_in[1];
    // d_in[2] = ba : constant along softmax axis -> cancels, unused
    const float* Wi  = (const float*)d_in[3];
    const float* Wh  = (const float*)d_in[4];
    const float* b   = (const float*)d_in[5];
    const float* Wvi = (const float*)d_in[6];
    const float* Wvh = (const float*)d_in[7];
    const float* bv  = (const float*)d_in[8];
    const float* Wfc = (const float*)d_in[9];
    const float* bfc = (const float*)d_in[10];

    float* hfinal = (float*)d_ws;                              // 128 KB
    float* ctx_ws = (float*)((char*)d_ws + 128 * 1024);        // 32 KB
    float* out    = (float*)d_out;

    ctx_kernel<<<BS, 256, 0, stream>>>(x, Wa, ctx_ws);
    rec_kernel<<<BS * 2, 512, 0, stream>>>(ctx_ws, Wi, Wh, b, Wvi, Wvh, bv, hfinal);
    chaotic_out<<<1, 512, 0, stream>>>(hfinal, Wfc, bfc, out);
}

// Round 5
// 68.649 us; speedup vs baseline: 1.0577x; 1.0577x over previous
//
#include <hip/hip_runtime.h>

#define BS   128
#define SEQ  64
#define DD   64
#define HH   128
#define G4   512   // 4*H
#define OUTN 4
#define MB   8     // batches per rec block (M of the MFMA actually used)

typedef float    f32x4 __attribute__((ext_vector_type(4)));
typedef unsigned u32x4 __attribute__((ext_vector_type(4)));
typedef _Float16 f16x8 __attribute__((ext_vector_type(8)));

__device__ __forceinline__ float sigm(float v) {
    return __builtin_amdgcn_rcpf(1.0f + __expf(-v));
}

// ============================================================================
// Kernel 1: attention context (state term constant over s -> cancels in the
// seq-softmax -> ctx is step-invariant). One block per batch. r11/r16-proven.
// ============================================================================
__global__ void __launch_bounds__(256) ctx_kernel(
    const float* __restrict__ x,    // [BS, SEQ, DD]
    const float* __restrict__ Wa,   // [DD+4H, DD] (rows >= DD cancel)
    float* __restrict__ ctx_ws)     // [BS, DD]
{
    const int batch = blockIdx.x;
    const int t     = threadIdx.x;
    const int lane  = t & 63;

    __shared__ float xs[SEQ * DD];
    __shared__ float was[DD * DD];
    __shared__ float xa[SEQ * DD];
    __shared__ float pmax[4 * 64], psum[4 * 64], pctx[4 * 64];
    __shared__ float fmx[DD];

    const float* xb = x + (size_t)batch * SEQ * DD;
    for (int i = t; i < SEQ * DD; i += 256) {
        xs[i]  = xb[i];
        was[i] = Wa[i];
    }
    __syncthreads();

    {   // XA = x_b @ Wa_x, register-tiled (d = lane, 16 s-rows)
        const int d  = lane;
        const int sb = (t >> 6) * 16;
        float acc[16];
        #pragma unroll
        for (int i = 0; i < 16; ++i) acc[i] = 0.0f;
        for (int kk = 0; kk < 16; ++kk) {
            float wk0 = was[(4 * kk + 0) * DD + d];
            float wk1 = was[(4 * kk + 1) * DD + d];
            float wk2 = was[(4 * kk + 2) * DD + d];
            float wk3 = was[(4 * kk + 3) * DD + d];
            #pragma unroll
            for (int i = 0; i < 16; ++i) {
                float4 xv = *(const float4*)&xs[(sb + i) * DD + 4 * kk];
                acc[i] = fmaf(xv.x, wk0, fmaf(xv.y, wk1,
                         fmaf(xv.z, wk2, fmaf(xv.w, wk3, acc[i]))));
            }
        }
        #pragma unroll
        for (int i = 0; i < 16; ++i) xa[(sb + i) * DD + d] = acc[i];
    }
    __syncthreads();

    {   // softmax partials over s
        const int d = lane, g4 = t >> 6;
        float m = -1e30f;
        #pragma unroll
        for (int j = 0; j < 16; ++j) m = fmaxf(m, xa[(g4 * 16 + j) * DD + d]);
        pmax[g4 * 64 + d] = m;
    }
    __syncthreads();
    if (t < DD) {
        float m = -1e30f;
        #pragma unroll
        for (int g = 0; g < 4; ++g) m = fmaxf(m, pmax[g * 64 + t]);
        fmx[t] = m;
    }
    __syncthreads();
    {
        const int d = lane, g4 = t >> 6;
        const float m = fmx[d];
        float sm = 0.0f, cc = 0.0f;
        #pragma unroll
        for (int j = 0; j < 16; ++j) {
            const int s = g4 * 16 + j;
            float e = __expf(xa[s * DD + d] - m);
            sm += e;
            cc += e * xs[s * DD + d];
        }
        psum[g4 * 64 + d] = sm;
        pctx[g4 * 64 + d] = cc;
    }
    __syncthreads();
    if (t < DD) {
        float sm = 0.0f, cc = 0.0f;
        #pragma unroll
        for (int g = 0; g < 4; ++g) { sm += psum[g * 64 + t]; cc += pctx[g * 64 + t]; }
        ctx_ws[batch * DD + t] = cc / sm;
    }
}

// ============================================================================
// Kernel 2: recurrence, M=8-BATCHED MFMA (round-4 structure). 32 blocks =
// 16 batch-groups x 2 cells, 512 threads (8 waves). Weights in B-fragments
// (16 x f16x8/lane, round-1-verified pattern); A = 8 h rows (batches) in LDS,
// row stride 272 B (2-way aliasing = free). Wave w owns h-cols w*16..+15;
// its 4 col-tiles ARE the 4 gates. C layout (m89): col=l&15, row=4*g8+reg.
// ROUND-4 BUGFIX: __shfl_xor was inside a ternary arm -> divergent bpermute
// sourced undefined data from inactive lanes (rows 2,3,6,7 garbage). Now all
// shfls execute UNCONDITIONALLY (uniform control flow), select afterwards.
// ============================================================================
__global__ void __launch_bounds__(512, 2) rec_kernel(
    const float* __restrict__ ctx_ws,   // [BS, DD]
    const float* __restrict__ Wi,  const float* __restrict__ Wh,
    const float* __restrict__ b,
    const float* __restrict__ Wvi, const float* __restrict__ Wvh,
    const float* __restrict__ bv,
    float* __restrict__ hfinal)         // [BS, 2H] f32
{
    const int grp  = blockIdx.x >> 1;   // batch-group 0..15 (MB batches each)
    const int cell = blockIdx.x & 1;
    const int t    = threadIdx.x;
    const int w    = t >> 6;            // wave 0..7
    const int l    = t & 63;
    const int c    = l & 15;            // column lane id (= A-row id on reads)
    const int g8   = l >> 4;            // k-group id / C row-group

    const float* __restrict__ Wx   = cell ? Wvi : Wi;
    const float* __restrict__ Whh  = cell ? Wvh : Wh;
    const float* __restrict__ bias = cell ? bv  : b;

    // h rows padded: 136 f16 = 272 B stride (68 dwords = 4 mod 32 -> 2-way free)
    __shared__ __align__(16) _Float16 hA[2][16][136];
    // ctx rows padded: 72 f16 = 144 B stride (36 dwords = 4 mod 32)
    __shared__ __align__(16) _Float16 ctxA[16][72];

    // zero h double-buffer (rows 8..15 stay zero forever) and ctxA
    {
        unsigned* hz = (unsigned*)hA;          // 2*16*136*2/4 = 2176 dwords
        for (int i = t; i < 2176; i += 512) hz[i] = 0u;
        unsigned* cz = (unsigned*)ctxA;        // 16*72*2/4 = 576 dwords
        for (int i = t; i < 576; i += 512) cz[i] = 0u;
    }
    __syncthreads();

    // stage ctx rows 0..7 (batches grp*MB..grp*MB+7) as f16
    if (t < 256) {
        const int r = t >> 5, dp = t & 31;     // row, dword-pair
        const float* cp = ctx_ws + (grp * MB + r) * DD + 2 * dp;
        union { unsigned u; _Float16 h[2]; } pk;
        pk.h[0] = (_Float16)cp[0];
        pk.h[1] = (_Float16)cp[1];
        ((unsigned*)ctxA)[r * 36 + dp] = pk.u;
    }
    __syncthreads();

    const int colbase = w * 16 + c;            // my owned h column (0..127)

    // ---- zcv[tau] = bias + ctx @ Wx (M=8 via MFMA, K=64), f32x4 C-init ----
    f32x4 zcv[4];
    {
        f16x8 a2[2];
        #pragma unroll
        for (int ks2 = 0; ks2 < 2; ++ks2)
            a2[ks2] = __builtin_bit_cast(f16x8,
                *(const u32x4*)((const char*)ctxA + c * 144 + ks2 * 64 + g8 * 16));
        #pragma unroll
        for (int tau = 0; tau < 4; ++tau) {
            float bb = bias[tau * HH + colbase];
            f32x4 acc = {bb, bb, bb, bb};
            #pragma unroll
            for (int ks2 = 0; ks2 < 2; ++ks2) {
                f16x8 bx;
                #pragma unroll
                for (int q = 0; q < 8; ++q)
                    bx[q] = (_Float16)Wx[(ks2 * 32 + g8 * 8 + q) * G4 + tau * HH + colbase];
                acc = __builtin_amdgcn_mfma_f32_16x16x32_f16(a2[ks2], bx, acc, 0, 0, 0);
            }
            zcv[tau] = acc;
        }
    }

    // ---- Whh B-fragments: 16 x f16x8 = 64 regs/lane (round-1 pattern) ----
    f16x8 bh[16];
    #pragma unroll
    for (int tau = 0; tau < 4; ++tau)
        #pragma unroll
        for (int ks = 0; ks < 4; ++ks) {
            f16x8 f;
            #pragma unroll
            for (int q = 0; q < 8; ++q)
                f[q] = (_Float16)Whh[(ks * 32 + g8 * 8 + q) * G4 + tau * HH + colbase];
            bh[tau * 4 + ks] = f;
        }

    // my two rows after the shfl spread: g8=0 -> {0,1}, 1 -> {4,5}, 2 -> {2,3}, 3 -> {6,7}
    const int r0 = 4 * (g8 & 1) + 2 * (g8 >> 1);

    float cA = 0.0f, cB = 0.0f, hlA = 0.0f, hlB = 0.0f;
    int pb = 0;
    __syncthreads();

    for (int step = 0; step < SEQ; ++step) {
        // A-frags: rows = c (batches 0..7 live, 8..15 zero), k-slice by ks,g8
        f16x8 A[4];
        #pragma unroll
        for (int ks = 0; ks < 4; ++ks)
            A[ks] = __builtin_bit_cast(f16x8,
                *(const u32x4*)((const char*)hA[pb] + c * 272 + ks * 64 + g8 * 16));

        f32x4 C0 = zcv[0], C1 = zcv[1], C2 = zcv[2], C3 = zcv[3];
        #pragma unroll
        for (int ks = 0; ks < 4; ++ks) {
            C0 = __builtin_amdgcn_mfma_f32_16x16x32_f16(A[ks], bh[0 * 4 + ks], C0, 0, 0, 0);
            C1 = __builtin_amdgcn_mfma_f32_16x16x32_f16(A[ks], bh[1 * 4 + ks], C1, 0, 0, 0);
            C2 = __builtin_amdgcn_mfma_f32_16x16x32_f16(A[ks], bh[2 * 4 + ks], C2, 0, 0, 0);
            C3 = __builtin_amdgcn_mfma_f32_16x16x32_f16(A[ks], bh[3 * 4 + ks], C3, 0, 0, 0);
        }

        // spread rows 2,3 / 6,7 from lane-groups 0,1 to 2,3 via lane^32.
        // ALL lanes execute every shfl (uniform control flow; sources always
        // active) — select AFTER. This is the round-4 correctness fix.
        const float s02 = __shfl_xor(C0[2], 32);
        const float s12 = __shfl_xor(C1[2], 32);
        const float s22 = __shfl_xor(C2[2], 32);
        const float s32 = __shfl_xor(C3[2], 32);
        const float s03 = __shfl_xor(C0[3], 32);
        const float s13 = __shfl_xor(C1[3], 32);
        const float s23 = __shfl_xor(C2[3], 32);
        const float s33 = __shfl_xor(C3[3], 32);

        const bool lo = (g8 < 2);
        const float qa0 = lo ? C0[0] : s02;
        const float qa1 = lo ? C1[0] : s12;
        const float qa2 = lo ? C2[0] : s22;
        const float qa3 = lo ? C3[0] : s32;
        const float qb0 = lo ? C0[1] : s03;
        const float qb1 = lo ? C1[1] : s13;
        const float qb2 = lo ? C2[1] : s23;
        const float qb3 = lo ? C3[1] : s33;

        // two independent LSTM pointwise chains (rows r0, r0+1)
        {
            const float tg = 2.0f * sigm(2.0f * qa2) - 1.0f;
            cA = sigm(qa1) * cA + sigm(qa0) * tg;
            hlA = sigm(qa3) * (2.0f * sigm(2.0f * cA) - 1.0f);
        }
        {
            const float tg = 2.0f * sigm(2.0f * qb2) - 1.0f;
            cB = sigm(qb1) * cB + sigm(qb0) * tg;
            hlB = sigm(qb3) * (2.0f * sigm(2.0f * cB) - 1.0f);
        }

        hA[pb ^ 1][r0    ][colbase] = (_Float16)hlA;
        hA[pb ^ 1][r0 + 1][colbase] = (_Float16)hlB;
        __syncthreads();
        pb ^= 1;
    }

    hfinal[(grp * MB + r0    ) * (2 * HH) + cell * HH + colbase] = hlA;
    hfinal[(grp * MB + r0 + 1) * (2 * HH) + cell * HH + colbase] = hlB;
}

// ============================================================================
// Kernel 3: out[b,o] = bfc[o] + sum_k hfinal[b,k] * Wfc[k,o]
// ============================================================================
__global__ void __launch_bounds__(512) chaotic_out(
    const float* __restrict__ hfinal,  // [BS, 2H] f32
    const float* __restrict__ Wfc,     // [2H, OUTN]
    const float* __restrict__ bfc,     // [OUTN]
    float* __restrict__ out)           // [BS, OUTN]
{
    int idx = threadIdx.x;
    if (idx >= BS * OUTN) return;
    const int bt = idx >> 2;
    const int o  = idx & 3;
    float acc = bfc[o];
    const float* hrow = hfinal + bt * (2 * HH);
    #pragma unroll 8
    for (int k = 0; k < 2 * HH; k++)
        acc = fmaf(hrow[k], Wfc[k * OUTN + o], acc);
    out[idx] = acc;
}

extern "C" void kernel_launch(void* const* d_in, const int* in_sizes, int n_in,
                              void* d_out, int out_size, void* d_ws, size_t ws_size,
                              hipStream_t stream) {
    const float* x   = (const float*)d_in[0];
    const float* Wa  = (const float*)d_in[1];
    // d_in[2] = ba : constant along softmax axis -> cancels, unused
    const float* Wi  = (const float*)d_in[3];
    const float* Wh  = (const float*)d_in[4];
    const float* b   = (const float*)d_in[5];
    const float* Wvi = (const float*)d_in[6];
    const float* Wvh = (const float*)d_in[7];
    const float* bv  = (const float*)d_in[8];
    const float* Wfc = (const float*)d_in[9];
    const float* bfc = (const float*)d_in[10];

    float* hfinal = (float*)d_ws;                              // 128 KB
    float* ctx_ws = (float*)((char*)d_ws + 128 * 1024);        // 32 KB
    float* out    = (float*)d_out;

    ctx_kernel<<<BS, 256, 0, stream>>>(x, Wa, ctx_ws);
    rec_kernel<<<(BS / MB) * 2, 512, 0, stream>>>(ctx_ws, Wi, Wh, b, Wvi, Wvh, bv, hfinal);
    chaotic_out<<<1, 512, 0, stream>>>(hfinal, Wfc, bfc, out);
}

// Round 6
// 59.091 us; speedup vs baseline: 1.2288x; 1.1618x over previous
//
#include <hip/hip_runtime.h>

#define BS   128
#define SEQ  64
#define DD   64
#define HH   128
#define G4   512   // 4*H
#define OUTN 4

typedef float    f32x4 __attribute__((ext_vector_type(4)));
typedef unsigned u32x4 __attribute__((ext_vector_type(4)));
typedef _Float16 f16x8 __attribute__((ext_vector_type(8)));
typedef _Float16 f16x2 __attribute__((ext_vector_type(2)));

__device__ __forceinline__ float sigm(float v) {
    return __builtin_amdgcn_rcpf(1.0f + __expf(-v));
}

// ============================================================================
// Kernel 1: attention context (state term constant over s -> cancels in the
// seq-softmax -> ctx is step-invariant). One block per batch. r11/r16-proven.
// ============================================================================
__global__ void __launch_bounds__(256) ctx_kernel(
    const float* __restrict__ x,    // [BS, SEQ, DD]
    const float* __restrict__ Wa,   // [DD+4H, DD] (rows >= DD cancel)
    float* __restrict__ ctx_ws)     // [BS, DD]
{
    const int batch = blockIdx.x;
    const int t     = threadIdx.x;
    const int lane  = t & 63;

    __shared__ float xs[SEQ * DD];
    __shared__ float was[DD * DD];
    __shared__ float xa[SEQ * DD];
    __shared__ float pmax[4 * 64], psum[4 * 64], pctx[4 * 64];
    __shared__ float fmx[DD];

    const float* xb = x + (size_t)batch * SEQ * DD;
    for (int i = t; i < SEQ * DD; i += 256) {
        xs[i]  = xb[i];
        was[i] = Wa[i];
    }
    __syncthreads();

    {   // XA = x_b @ Wa_x, register-tiled (d = lane, 16 s-rows)
        const int d  = lane;
        const int sb = (t >> 6) * 16;
        float acc[16];
        #pragma unroll
        for (int i = 0; i < 16; ++i) acc[i] = 0.0f;
        for (int kk = 0; kk < 16; ++kk) {
            float wk0 = was[(4 * kk + 0) * DD + d];
            float wk1 = was[(4 * kk + 1) * DD + d];
            float wk2 = was[(4 * kk + 2) * DD + d];
            float wk3 = was[(4 * kk + 3) * DD + d];
            #pragma unroll
            for (int i = 0; i < 16; ++i) {
                float4 xv = *(const float4*)&xs[(sb + i) * DD + 4 * kk];
                acc[i] = fmaf(xv.x, wk0, fmaf(xv.y, wk1,
                         fmaf(xv.z, wk2, fmaf(xv.w, wk3, acc[i]))));
            }
        }
        #pragma unroll
        for (int i = 0; i < 16; ++i) xa[(sb + i) * DD + d] = acc[i];
    }
    __syncthreads();

    {   // softmax partials over s
        const int d = lane, g4 = t >> 6;
        float m = -1e30f;
        #pragma unroll
        for (int j = 0; j < 16; ++j) m = fmaxf(m, xa[(g4 * 16 + j) * DD + d]);
        pmax[g4 * 64 + d] = m;
    }
    __syncthreads();
    if (t < DD) {
        float m = -1e30f;
        #pragma unroll
        for (int g = 0; g < 4; ++g) m = fmaxf(m, pmax[g * 64 + t]);
        fmx[t] = m;
    }
    __syncthreads();
    {
        const int d = lane, g4 = t >> 6;
        const float m = fmx[d];
        float sm = 0.0f, cc = 0.0f;
        #pragma unroll
        for (int j = 0; j < 16; ++j) {
            const int s = g4 * 16 + j;
            float e = __expf(xa[s * DD + d] - m);
            sm += e;
            cc += e * xs[s * DD + d];
        }
        psum[g4 * 64 + d] = sm;
        pctx[g4 * 64 + d] = cc;
    }
    __syncthreads();
    if (t < DD) {
        float sm = 0.0f, cc = 0.0f;
        #pragma unroll
        for (int g = 0; g < 4; ++g) { sm += psum[g * 64 + t]; cc += pctx[g * 64 + t]; }
        ctx_ws[batch * DD + t] = cc / sm;
    }
}

// ============================================================================
// Kernel 2: recurrence — ROUND-1 VERIFIED STRUCTURE (41.1 us) with ONE change:
// the 4-deep dependent MFMA chain per gate is replaced by 16 INDEPENDENT
// accumulators (C-init = zcv for ks=0, zero otherwise) + a scalar add-tree on
// the [0] elements only. Hypothesis: dependent-MFMA latency (~100cy?) put
// ~300-400cy of the 1540cy step on the critical path; independence removes it
// for ~60cy of extra VALU. Everything else byte-identical to round 1:
// 512 thr / 8 waves, wave w owns h-cols w*16..+15, col-tiles ARE the gates,
// broadcast A-reads, zc pre-folded, 1 barrier/step, dbuf h in LDS.
// ============================================================================
__global__ void __launch_bounds__(512, 2) rec_kernel(
    const float* __restrict__ ctx_ws,   // [BS, DD]
    const float* __restrict__ Wi,  const float* __restrict__ Wh,
    const float* __restrict__ b,
    const float* __restrict__ Wvi, const float* __restrict__ Wvh,
    const float* __restrict__ bv,
    float* __restrict__ hfinal)         // [BS, 2H] f32
{
    const int batch = blockIdx.x >> 1;
    const int cell  = blockIdx.x & 1;
    const int t     = threadIdx.x;
    const int w     = t >> 6;           // wave 0..7
    const int l     = t & 63;
    const int c     = l & 15;           // B/C column lane id
    const int g     = l >> 4;           // k-group id

    const float* __restrict__ Wx   = cell ? Wvi : Wi;
    const float* __restrict__ Whh  = cell ? Wvh : Wh;
    const float* __restrict__ bias = cell ? bv  : b;

    __shared__ __align__(16) _Float16 ctxA[64];   // 1 row x 64 k (f16)
    __shared__ __align__(16) _Float16 h2[2][HH];  // dbuf h (f16)

    // stage ctx row (32 packed dwords); zero BOTH h buffers (128 dwords)
    if (t < 32) {
        f16x2 p;
        p.x = (_Float16)ctx_ws[batch * DD + 2 * t];
        p.y = (_Float16)ctx_ws[batch * DD + 2 * t + 1];
        ((unsigned*)ctxA)[t] = __builtin_bit_cast(unsigned, p);
    }
    if (t >= 64 && t < 192) ((unsigned*)h2)[t - 64] = 0u;

    const int colbase = w * 16 + c;     // my owned h column (0..127)

    __syncthreads();

    // ---- zcv[tau] = bias + ctx @ Wx for col tau*HH+j (rows duplicated,
    //      so zcv[tau] = {z,z,z,z} -> usable directly as MFMA C-init) ----
    f32x4 zcv[4];
    {
        f16x8 ax[2];
        #pragma unroll
        for (int ks = 0; ks < 2; ++ks)
            ax[ks] = __builtin_bit_cast(f16x8,
                *(const u32x4*)((const unsigned*)ctxA + ks * 16 + g * 4));
        #pragma unroll
        for (int tau = 0; tau < 4; ++tau) {
            float bb = bias[tau * HH + colbase];
            f32x4 acc = {bb, bb, bb, bb};
            #pragma unroll
            for (int ks = 0; ks < 2; ++ks) {
                f16x8 bx;
                #pragma unroll
                for (int q = 0; q < 8; ++q)
                    bx[q] = (_Float16)Wx[(ks * 32 + g * 8 + q) * G4 + tau * HH + colbase];
                acc = __builtin_amdgcn_mfma_f32_16x16x32_f16(ax[ks], bx, acc, 0, 0, 0);
            }
            zcv[tau] = acc;
        }
    }

    // ---- Whh B-fragments: 16 x f16x8 = 64 regs/lane, register-resident ----
    f16x8 bh[16];
    #pragma unroll
    for (int tau = 0; tau < 4; ++tau)
        #pragma unroll
        for (int ks = 0; ks < 4; ++ks) {
            f16x8 f;
            #pragma unroll
            for (int q = 0; q < 8; ++q)
                f[q] = (_Float16)Whh[(ks * 32 + g * 8 + q) * G4 + tau * HH + colbase];
            bh[tau * 4 + ks] = f;
        }

    const f32x4 zero4 = {0.0f, 0.0f, 0.0f, 0.0f};
    float c_state = 0.0f, h_last = 0.0f;
    int pb = 0;

    for (int step = 0; step < SEQ; ++step) {
        // A-frags: single h row, 4 distinct 16B addrs (disjoint banks), broadcast
        const unsigned* hb = (const unsigned*)h2[pb];
        f16x8 A[4];
        #pragma unroll
        for (int ks = 0; ks < 4; ++ks)
            A[ks] = __builtin_bit_cast(f16x8, *(const u32x4*)(hb + ks * 16 + g * 4));

        // 16 INDEPENDENT MFMAs — no accumulator chaining (the round-6 change)
        f32x4 P00 = __builtin_amdgcn_mfma_f32_16x16x32_f16(A[0], bh[ 0], zcv[0], 0, 0, 0);
        f32x4 P01 = __builtin_amdgcn_mfma_f32_16x16x32_f16(A[1], bh[ 1], zero4,  0, 0, 0);
        f32x4 P02 = __builtin_amdgcn_mfma_f32_16x16x32_f16(A[2], bh[ 2], zero4,  0, 0, 0);
        f32x4 P03 = __builtin_amdgcn_mfma_f32_16x16x32_f16(A[3], bh[ 3], zero4,  0, 0, 0);
        f32x4 P10 = __builtin_amdgcn_mfma_f32_16x16x32_f16(A[0], bh[ 4], zcv[1], 0, 0, 0);
        f32x4 P11 = __builtin_amdgcn_mfma_f32_16x16x32_f16(A[1], bh[ 5], zero4,  0, 0, 0);
        f32x4 P12 = __builtin_amdgcn_mfma_f32_16x16x32_f16(A[2], bh[ 6], zero4,  0, 0, 0);
        f32x4 P13 = __builtin_amdgcn_mfma_f32_16x16x32_f16(A[3], bh[ 7], zero4,  0, 0, 0);
        f32x4 P20 = __builtin_amdgcn_mfma_f32_16x16x32_f16(A[0], bh[ 8], zcv[2], 0, 0, 0);
        f32x4 P21 = __builtin_amdgcn_mfma_f32_16x16x32_f16(A[1], bh[ 9], zero4,  0, 0, 0);
        f32x4 P22 = __builtin_amdgcn_mfma_f32_16x16x32_f16(A[2], bh[10], zero4,  0, 0, 0);
        f32x4 P23 = __builtin_amdgcn_mfma_f32_16x16x32_f16(A[3], bh[11], zero4,  0, 0, 0);
        f32x4 P30 = __builtin_amdgcn_mfma_f32_16x16x32_f16(A[0], bh[12], zcv[3], 0, 0, 0);
        f32x4 P31 = __builtin_amdgcn_mfma_f32_16x16x32_f16(A[1], bh[13], zero4,  0, 0, 0);
        f32x4 P32 = __builtin_amdgcn_mfma_f32_16x16x32_f16(A[2], bh[14], zero4,  0, 0, 0);
        f32x4 P33 = __builtin_amdgcn_mfma_f32_16x16x32_f16(A[3], bh[15], zero4,  0, 0, 0);

        // gates: scalar add-tree on element 0 only (all C rows are duplicates)
        const float gi = (P00[0] + P01[0]) + (P02[0] + P03[0]);
        const float gf = (P10[0] + P11[0]) + (P12[0] + P13[0]);
        const float gg = (P20[0] + P21[0]) + (P22[0] + P23[0]);
        const float go = (P30[0] + P31[0]) + (P32[0] + P33[0]);

        const float tg = 2.0f * sigm(2.0f * gg) - 1.0f;             // tanh(g)
        c_state  = sigm(gf) * c_state + sigm(gi) * tg;
        const float hn = sigm(go) * (2.0f * sigm(2.0f * c_state) - 1.0f);
        h_last = hn;

        if (g == 0)
            h2[pb ^ 1][colbase] = (_Float16)hn;
        __syncthreads();
        pb ^= 1;
    }

    if (g == 0)
        hfinal[batch * (2 * HH) + cell * HH + colbase] = h_last;
}

// ============================================================================
// Kernel 3: out[b,o] = bfc[o] + sum_k hfinal[b,k] * Wfc[k,o]
// ============================================================================
__global__ void __launch_bounds__(512) chaotic_out(
    const float* __restrict__ hfinal,  // [BS, 2H] f32
    const float* __restrict__ Wfc,     // [2H, OUTN]
    const float* __restrict__ bfc,     // [OUTN]
    float* __restrict__ out)           // [BS, OUTN]
{
    int idx = threadIdx.x;
    if (idx >= BS * OUTN) return;
    const int bt = idx >> 2;
    const int o  = idx & 3;
    float acc = bfc[o];
    const float* hrow = hfinal + bt * (2 * HH);
    #pragma unroll 8
    for (int k = 0; k < 2 * HH; k++)
        acc = fmaf(hrow[k], Wfc[k * OUTN + o], acc);
    out[idx] = acc;
}

extern "C" void kernel_launch(void* const* d_in, const int* in_sizes, int n_in,
                              void* d_out, int out_size, void* d_ws, size_t ws_size,
                              hipStream_t stream) {
    const float* x   = (const float*)d_in[0];
    const float* Wa  = (const float*)d_in[1];
    // d_in[2] = ba : constant along softmax axis -> cancels, unused
    const float* Wi  = (const float*)d_in[3];
    const float* Wh  = (const float*)d_in[4];
    const float* b   = (const float*)d_in[5];
    const float* Wvi = (const float*)d_in[6];
    const float* Wvh = (const float*)d_in[7];
    const float* bv  = (const float*)d_in[8];
    const float* Wfc = (const float*)d_in[9];
    const float* bfc = (const float*)d_in[10];

    float* hfinal = (float*)d_ws;                              // 128 KB
    float* ctx_ws = (float*)((char*)d_ws + 128 * 1024);        // 32 KB
    float* out    = (float*)d_out;

    ctx_kernel<<<BS, 256, 0, stream>>>(x, Wa, ctx_ws);
    rec_kernel<<<BS * 2, 512, 0, stream>>>(ctx_ws, Wi, Wh, b, Wvi, Wvh, bv, hfinal);
    chaotic_out<<<1, 512, 0, stream>>>(hfinal, Wfc, bfc, out);
}